// Round 2
// baseline (218.883 us; speedup 1.0000x reference)
//
#include <hip/hip_runtime.h>

// Problem constants (B=16, D=128, H=32, W=32, K=8192)
#define D 128
#define HW 1024
#define NROWS 16384
#define K 8192
#define NU 32   // 32-col units per block (1024-col k-split / 32)

// d_out layout (float offsets): z_q_st | indices | new_codebook | new_count | new_weight
#define OUT0 0
#define OUT1 2097152
#define OUT2 2113536
#define OUT3 3162112
#define OUT4 3170304

typedef __attribute__((ext_vector_type(8))) _Float16 half8;
typedef __attribute__((ext_vector_type(16))) float f32x16;
typedef unsigned short u16;
typedef unsigned long long u64;

// ---- async global->LDS, 16B per lane (dst = wave-uniform base + lane*16) ----
__device__ __forceinline__ void gld16(const u16* gsrc, u16* ldst) {
    __builtin_amdgcn_global_load_lds(
        (const __attribute__((address_space(1))) unsigned int*)gsrc,
        (__attribute__((address_space(3))) unsigned int*)ldst,
        16, 0, 0);
}

// ---- fused prep: blocks [0,512) codebook-split + cnorm + dw-zero;
//      blocks [512,1536) z-split + packed-init + counts-zero ----
// B layout: [unit g(256)][ Bh: [kk(16)][col(32)][j(8)] | Bl: same ] (16 KiB/unit)
// A layout: [band(n>>5)][ks(8)][lh(2)][row(32)][j(8)]
__global__ __launch_bounds__(256) void k_prep(const float* __restrict__ cb,
                                              const float* __restrict__ z_e,
                                              u16* __restrict__ Bg,
                                              float* __restrict__ cnorm,
                                              u16* __restrict__ Ah, u16* __restrict__ Al,
                                              u64* __restrict__ packed,
                                              float* __restrict__ counts,
                                              float* __restrict__ dw) {
    const int tid = threadIdx.x;
    if (blockIdx.x < 512) {
        int kk = tid & 15;
        int k = blockIdx.x * 16 + (tid >> 4);
        const float* src = cb + (size_t)k * D + kk * 8;
        half8 h, l;
        float s = 0.f;
#pragma unroll
        for (int j = 0; j < 8; ++j) {
            float v = src[j];
            s += v * v;
            _Float16 hv = (_Float16)v;              // RN f32->f16
            _Float16 lv = (_Float16)(v - (float)hv);
            h[j] = hv;
            l[j] = lv;
        }
        int g = k >> 5, col = k & 31;
        size_t offH = (size_t)g * 8192 + ((size_t)kk * 32 + col) * 8;
        *(half8*)((_Float16*)Bg + offH) = h;
        *(half8*)((_Float16*)Bg + offH + 4096) = l;
#pragma unroll
        for (int off = 8; off > 0; off >>= 1) s += __shfl_down(s, off);
        if (kk == 0) cnorm[k] = s;
        // zero dw: 131072 threads x 8 floats = K*D exactly
        float4 z4 = {0.f, 0.f, 0.f, 0.f};
        size_t zi = ((size_t)blockIdx.x * 256 + tid) * 8;
        *(float4*)(dw + zi) = z4;
        *(float4*)(dw + zi + 4) = z4;
    } else {
        int gid = (blockIdx.x - 512) * 256 + tid;   // NROWS*16 threads
        int n  = gid & (NROWS - 1);                 // lane-contiguous n -> coalesced
        int kk = gid >> 14;                         // 0..15
        int b = n >> 10, hw = n & 1023;
        const float* src = z_e + ((size_t)b * D + kk * 8) * HW + hw;
        half8 h, l;
#pragma unroll
        for (int j = 0; j < 8; ++j) {
            float v = src[(size_t)j * HW];
            _Float16 hv = (_Float16)v;
            _Float16 lv = (_Float16)(v - (float)hv);
            h[j] = hv;
            l[j] = lv;
        }
        int rg = n >> 7, band = (n >> 5) & 3, row = n & 31;
        size_t off = (((((size_t)rg * 4 + band) * 8 + (kk >> 1)) * 2 + (kk & 1)) * 32 + row) * 8;
        *(half8*)(Ah + off) = h;
        *(half8*)(Al + off) = l;
        if (kk == 0) {
            packed[n] = ~0ull;                      // +inf sentinel
            if (n < K) counts[n] = 0.f;
        }
    }
}

// ---- main: 3-pass fp16-split distance GEMM + fused argmin ----
// grid: 128 rowgroups x 8 ksplits = 1024 blocks, 256 threads (4 waves).
// Wave tile: 32 rows x 32 cols. A-frags pinned in VGPRs; B in 32-col units,
// 2x16 KiB LDS dbuf -> 3-4 blocks/CU (narrow 4-wave barrier groups, de-phased
// across blocks). Counted vmcnt(4) keeps next unit's stage in flight across
// the raw s_barrier. Two independent acc chains break the 24-long MFMA
// dependency chain; launch_bounds(256,3) leaves ~30 regs of ds_read-hoist
// headroom (R0 sat at exactly the 128-reg cap -> no hoisting possible).
__global__ __launch_bounds__(256, 3) void k_argmin_mfma(
        const u16* __restrict__ Ahg, const u16* __restrict__ Alg,
        const u16* __restrict__ Bg,
        const float* __restrict__ cnorm, u64* __restrict__ packed) {
    __shared__ u16 lds[2][8192];                // 2 x 16 KiB

    const int tid = threadIdx.x;
    const int ln  = tid & 63;
    const int l31 = ln & 31;
    const int lh  = ln >> 5;                    // k-half select within frag
    const int wy  = tid >> 6;                   // row band 0..3

    const int rg = blockIdx.x >> 3;             // 128 row groups x 128 rows
    const int k0 = (blockIdx.x & 7) * 1024;     // k split
    const int g0 = k0 >> 5;                     // first 32-col B-unit

    // ---- A fragments -> registers (read once from global; 64 VGPRs) ----
    half8 Ah[8], Al[8];
#pragma unroll
    for (int ks = 0; ks < 8; ++ks) {
        size_t off = ((((size_t)(rg * 4 + wy) * 8 + ks) * 2 + lh) * 32 + l31) * 8;
        Ah[ks] = *(const half8*)((const _Float16*)Ahg + off);
        Al[ks] = *(const half8*)((const _Float16*)Alg + off);
    }

    // ---- prologue: stage unit 0 (16 KiB, 4 gld16/thread) ----
    {
        const u16* src = Bg + (size_t)g0 * 8192;
#pragma unroll
        for (int r = 0; r < 4; ++r)
            gld16(src + ((size_t)r * 256 + tid) * 8, lds[0] + (r * 256 + tid) * 8);
    }

    float minv[16];
    int   mini[16];
#pragma unroll
    for (int r = 0; r < 16; ++r) { minv[r] = INFINITY; mini[r] = 0; }

#pragma unroll 1
    for (int u = 0; u < NU; ++u) {
        const u16* buf = lds[u & 1];
        const int c0 = k0 + u * 32 + l31;

        // cn load issued with the stage ops; its use is compiler-tracked
        float cn0 = cnorm[c0];

        if (u + 1 < NU) {
            const u16* src = Bg + (size_t)(g0 + u + 1) * 8192;
            u16* dst = lds[(u + 1) & 1];
#pragma unroll
            for (int r = 0; r < 4; ++r)
                gld16(src + ((size_t)r * 256 + tid) * 8, dst + (r * 256 + tid) * 8);
            // wait for *this* unit's stage; next unit's 4 loads stay in flight
            asm volatile("s_waitcnt vmcnt(4)" ::: "memory");
        } else {
            asm volatile("s_waitcnt vmcnt(0)" ::: "memory");
        }
        asm volatile("s_barrier" ::: "memory");

        f32x16 accA = {}, accB = {};
        const _Float16* bh = (const _Float16*)buf;
        const _Float16* bl = bh + 4096;

        __builtin_amdgcn_s_setprio(1);
        // pass 1: Ah x Bl -> chain A
#pragma unroll
        for (int ks = 0; ks < 8; ++ks) {
            const int bo = ((ks * 2 + lh) * 32 + l31) * 8;
            half8 b0 = *(const half8*)(bl + bo);
            accA = __builtin_amdgcn_mfma_f32_32x32x16_f16(Ah[ks], b0, accA, 0, 0, 0);
        }
        // passes 2+3: Ah x Bh -> chain B, Al x Bh -> chain A (2-way ILP per iter)
#pragma unroll
        for (int ks = 0; ks < 8; ++ks) {
            const int bo = ((ks * 2 + lh) * 32 + l31) * 8;
            half8 b0 = *(const half8*)(bh + bo);
            accB = __builtin_amdgcn_mfma_f32_32x32x16_f16(Ah[ks], b0, accB, 0, 0, 0);
            accA = __builtin_amdgcn_mfma_f32_32x32x16_f16(Al[ks], b0, accA, 0, 0, 0);
        }
        __builtin_amdgcn_s_setprio(0);

        // fold dist = cnorm - 2*(accA+accB) into running argmin
#pragma unroll
        for (int r = 0; r < 16; ++r) {
            float d0 = fmaf(-2.0f, accA[r] + accB[r], cn0);
            if (d0 < minv[r]) { minv[r] = d0; mini[r] = c0; }
        }
        // all waves done reading buf before its sibling is overwritten next iter
        asm volatile("s_barrier" ::: "memory");
    }

    // ---- reduce across the 32 l31-lanes sharing each output row ----
#pragma unroll
    for (int r = 0; r < 16; ++r) {
        float v = minv[r];
        int ix = mini[r];
#pragma unroll
        for (int off = 1; off < 32; off <<= 1) {
            float v2 = __shfl_xor(v, off);
            int i2 = __shfl_xor(ix, off);
            if (v2 < v || (v2 == v && i2 < ix)) { v = v2; ix = i2; }
        }
        if (l31 == 0) {
            // C/D row map (m74/m101): row = (reg&3) + 8*(reg>>2) + 4*(lane>>5)
            int row = rg * 128 + wy * 32 + 4 * lh + (r & 3) + 8 * (r >> 2);
            unsigned int uenc = __float_as_uint(v);
            uenc = (uenc & 0x80000000u) ? ~uenc : (uenc | 0x80000000u);  // monotonic
            u64 pk = ((u64)uenc << 13) | (u64)(unsigned)ix;
            atomicMin(&packed[row], pk);
        }
    }
}

// ---- epilogue: indices, z_q_st, counts, dw ----
__global__ __launch_bounds__(256) void k_epilogue(const float* __restrict__ z_e,
                                                  const float* __restrict__ cb,
                                                  const u64* __restrict__ packed,
                                                  float* __restrict__ out0,
                                                  float* __restrict__ out1,
                                                  float* __restrict__ counts,
                                                  float* __restrict__ dw) {
    __shared__ int idxS[64];
    const int tid = threadIdx.x;
    const int n0 = blockIdx.x * 64;
    const int bb = n0 >> 10, p0 = n0 & 1023;

    if (tid < 64) {
        int ix = (int)(packed[n0 + tid] & 0x1FFFull);
        idxS[tid] = ix;
        out1[n0 + tid] = (float)ix;
        atomicAdd(&counts[ix], 1.0f);
    }
    __syncthreads();

    const float* zb = z_e + (size_t)bb * (D * HW) + p0;
    float* ob = out0 + (size_t)bb * (D * HW) + p0;

    for (int i = tid; i < 64 * D; i += 256) {
        int d = i >> 6, r = i & 63;
        float z = zb[(size_t)d * HW + r];
        float c = cb[(size_t)idxS[r] * D + d];
        ob[(size_t)d * HW + r] = z + (c - z);
    }
    for (int i = tid; i < 64 * D; i += 256) {
        int r = i >> 7, d = i & 127;
        atomicAdd(&dw[(size_t)idxS[r] * D + d], zb[(size_t)d * HW + r]);
    }
}

__global__ __launch_bounds__(256) void k_final(const float* __restrict__ ema_count,
                                               const float* __restrict__ ema_weight,
                                               float* __restrict__ out2,
                                               float* __restrict__ out3,
                                               float* __restrict__ out4) {
    int gid = blockIdx.x * 256 + threadIdx.x;   // over K*D
    int k = gid >> 7, d = gid & 127;
    float cnt_raw = out3[k];
    float dw_raw = out4[gid];
    __syncthreads();
    float nc = 0.99f * ema_count[k] + 0.01f * cnt_raw;
    float nw = 0.99f * ema_weight[gid] + 0.01f * dw_raw;
    out4[gid] = nw;
    out2[gid] = nw / fmaxf(nc, 1.0f);
    if (d == 0) out3[k] = nc;
}

extern "C" void kernel_launch(void* const* d_in, const int* in_sizes, int n_in,
                              void* d_out, int out_size, void* d_ws, size_t ws_size,
                              hipStream_t stream) {
    const float* z_e        = (const float*)d_in[0];
    const float* cb         = (const float*)d_in[1];
    const float* ema_count  = (const float*)d_in[2];
    const float* ema_weight = (const float*)d_in[3];
    float* out = (float*)d_out;

    float* cnorm = (float*)d_ws;                                   // K floats
    u64* packed = (u64*)((char*)d_ws + K * 4);                     // NROWS u64

    // fp16-split scratch lives in out regions rewritten later:
    // out0 (8 MB) hosts Ah|Al, out2 (4 MB) hosts the unit-interleaved B.
    u16* Ahg = (u16*)(out + OUT0);
    u16* Alg = Ahg + (size_t)NROWS * D;
    u16* Bg  = (u16*)(out + OUT2);                                 // 256 units x 16 KiB

    k_prep       <<<1536,          256, 0, stream>>>(cb, z_e, Bg, cnorm, Ahg, Alg,
                                                     packed, out + OUT3, out + OUT4);
    k_argmin_mfma<<<1024,          256, 0, stream>>>(Ahg, Alg, Bg, cnorm, packed);
    k_epilogue   <<<NROWS / 64,    256, 0, stream>>>(z_e, cb, packed,
                                                     out + OUT0, out + OUT1,
                                                     out + OUT3, out + OUT4);
    k_final      <<<(K * D) / 256, 256, 0, stream>>>(ema_count, ema_weight,
                                                     out + OUT2, out + OUT3, out + OUT4);
}

// Round 4
// 215.053 us; speedup vs baseline: 1.0178x; 1.0178x over previous
//
#include <hip/hip_runtime.h>

// Problem constants (B=16, D=128, H=32, W=32, K=8192)
#define D 128
#define HW 1024
#define NROWS 16384
#define K 8192
#define NU 32   // 32-col units per block (1024-col k-split / 32)

// d_out layout (float offsets): z_q_st | indices | new_codebook | new_count | new_weight
#define OUT0 0
#define OUT1 2097152
#define OUT2 2113536
#define OUT3 3162112
#define OUT4 3170304

typedef __attribute__((ext_vector_type(8))) _Float16 half8;
typedef __attribute__((ext_vector_type(16))) float f32x16;
typedef unsigned short u16;
typedef unsigned long long u64;

// ---- async global->LDS, 16B per lane (dst = wave-uniform base + lane*16) ----
__device__ __forceinline__ void gld16(const u16* gsrc, u16* ldst) {
    __builtin_amdgcn_global_load_lds(
        (const __attribute__((address_space(1))) unsigned int*)gsrc,
        (__attribute__((address_space(3))) unsigned int*)ldst,
        16, 0, 0);
}

// ---- fused prep: blocks [0,512) codebook-split + cnorm + dw-zero;
//      blocks [512,1536) z-split + packed-init + counts-zero ----
// B layout: [unit g(256)][ Bh: [kk(16)][col(32)][j(8)] | Bl: same ] (16 KiB/unit)
// A layout: [band(n>>5)][ks(8)][lh(2)][row(32)][j(8)]
__global__ __launch_bounds__(256) void k_prep(const float* __restrict__ cb,
                                              const float* __restrict__ z_e,
                                              u16* __restrict__ Bg,
                                              float* __restrict__ cnorm,
                                              u16* __restrict__ Ah, u16* __restrict__ Al,
                                              u64* __restrict__ packed,
                                              float* __restrict__ counts,
                                              float* __restrict__ dw) {
    const int tid = threadIdx.x;
    if (blockIdx.x < 512) {
        int kk = tid & 15;
        int k = blockIdx.x * 16 + (tid >> 4);
        const float* src = cb + (size_t)k * D + kk * 8;
        half8 h, l;
        float s = 0.f;
#pragma unroll
        for (int j = 0; j < 8; ++j) {
            float v = src[j];
            s += v * v;
            _Float16 hv = (_Float16)v;              // RN f32->f16
            _Float16 lv = (_Float16)(v - (float)hv);
            h[j] = hv;
            l[j] = lv;
        }
        int g = k >> 5, col = k & 31;
        size_t offH = (size_t)g * 8192 + ((size_t)kk * 32 + col) * 8;
        *(half8*)((_Float16*)Bg + offH) = h;
        *(half8*)((_Float16*)Bg + offH + 4096) = l;
#pragma unroll
        for (int off = 8; off > 0; off >>= 1) s += __shfl_down(s, off);
        if (kk == 0) cnorm[k] = s;
        // zero dw: 131072 threads x 8 floats = K*D exactly
        float4 z4 = {0.f, 0.f, 0.f, 0.f};
        size_t zi = ((size_t)blockIdx.x * 256 + tid) * 8;
        *(float4*)(dw + zi) = z4;
        *(float4*)(dw + zi + 4) = z4;
    } else {
        int gid = (blockIdx.x - 512) * 256 + tid;   // NROWS*16 threads
        int n  = gid & (NROWS - 1);                 // lane-contiguous n -> coalesced
        int kk = gid >> 14;                         // 0..15
        int b = n >> 10, hw = n & 1023;
        const float* src = z_e + ((size_t)b * D + kk * 8) * HW + hw;
        half8 h, l;
#pragma unroll
        for (int j = 0; j < 8; ++j) {
            float v = src[(size_t)j * HW];
            _Float16 hv = (_Float16)v;
            _Float16 lv = (_Float16)(v - (float)hv);
            h[j] = hv;
            l[j] = lv;
        }
        int rg = n >> 7, band = (n >> 5) & 3, row = n & 31;
        size_t off = (((((size_t)rg * 4 + band) * 8 + (kk >> 1)) * 2 + (kk & 1)) * 32 + row) * 8;
        *(half8*)(Ah + off) = h;
        *(half8*)(Al + off) = l;
        if (kk == 0) {
            packed[n] = ~0ull;                      // +inf sentinel
            if (n < K) counts[n] = 0.f;
        }
    }
}

// ---- main: 3-pass fp16-split distance GEMM + fused argmin, 8-phase-style ----
// grid: 64 rowgroups (256 rows) x 8 ksplits = 512 blocks, 512 threads (8 waves,
// wy=row band). Wave tile 32x32; A-frags in regs; B in 32-col (16 KiB) units on
// a 3-deep LDS ring (48 KiB). Each unit = 2 template phases:
//   {8 ds_read ; 1 gld16(u+2) ; barrier ; setprio+MFMA ; barrier}
// with ONE counted vmcnt(3) per unit. Steady-state count is exact regardless of
// compiler VMEM issue order (exactly 3 VMEM ops per unit between asm fences).
// Prologue drains vmcnt(0) -- counted there was order-dependent (R3 hazard).
__global__ __launch_bounds__(512, 2) void k_argmin_mfma(
        const u16* __restrict__ Ahg, const u16* __restrict__ Alg,
        const u16* __restrict__ Bg,
        const float* __restrict__ cnorm, u64* __restrict__ packed) {
    extern __shared__ u16 smem[];               // 3 x 16 KiB ring

    const int tid = threadIdx.x;
    const int ln  = tid & 63;
    const int l31 = ln & 31;
    const int lh  = ln >> 5;                    // k-half select within frag
    const int wy  = tid >> 6;                   // row band 0..7

    const int rg = blockIdx.x >> 3;             // 64 row groups x 256 rows
    const int k0 = (blockIdx.x & 7) * 1024;     // k split; bid%8 -> XCD-pinned B slice
    const int g0 = k0 >> 5;                     // first 32-col B-unit
    const int band = rg * 8 + wy;               // global 32-row band 0..511

    // ---- A fragments -> registers (read once from global; 64 VGPRs) ----
    half8 Ah[8], Al[8];
#pragma unroll
    for (int ks = 0; ks < 8; ++ks) {
        size_t off = ((((size_t)band * 8 + ks) * 2 + lh) * 32 + l31) * 8;
        Ah[ks] = *(const half8*)((const _Float16*)Ahg + off);
        Al[ks] = *(const half8*)((const _Float16*)Alg + off);
    }

    // ---- prologue: stage units 0,1 into ring slabs 0,1; cn pipeline 2 deep ----
    {
        const u16* s0 = Bg + (size_t)g0 * 8192;
        gld16(s0 + (size_t)tid * 8,         smem + (size_t)tid * 8);
        gld16(s0 + (size_t)(512 + tid) * 8, smem + (size_t)(512 + tid) * 8);
        const u16* s1 = s0 + 8192;
        gld16(s1 + (size_t)tid * 8,         smem + 8192 + (size_t)tid * 8);
        gld16(s1 + (size_t)(512 + tid) * 8, smem + 8192 + (size_t)(512 + tid) * 8);
    }
    float cn_cur = cnorm[k0 + l31];
    float cn_nxt = cnorm[k0 + 32 + l31];
    // full drain: robust under any compiler VMEM issue order (prologue only)
    asm volatile("s_waitcnt vmcnt(0)" ::: "memory");
    asm volatile("s_barrier" ::: "memory");

    float minv[16];
    int   mini[16];
#pragma unroll
    for (int r = 0; r < 16; ++r) { minv[r] = INFINITY; mini[r] = 0; }

    u16* bufA = smem;                // current unit
    u16* bufB = smem + 8192;         // next unit
    u16* bufC = smem + 16384;        // staging target (u+2)

#pragma unroll 1
    for (int u = 0; u < NU; ++u) {
        const _Float16* bh = (const _Float16*)bufA;
        const _Float16* bl = bh + 4096;
        const int c0 = k0 + u * 32 + l31;
        const bool pf = (u + 2 < NU);
        const u16* src = Bg + (size_t)(g0 + u + 2) * 8192;

        f32x16 acc = {};

        // ---- phase 1: Bl frag reads + first stage half -> barrier -> 8 MFMA ----
        half8 b0[8];
#pragma unroll
        for (int ks = 0; ks < 8; ++ks)
            b0[ks] = *(const half8*)(bl + ((ks * 2 + lh) * 32 + l31) * 8);
        if (pf) gld16(src + (size_t)tid * 8, bufC + (size_t)tid * 8);
        asm volatile("s_barrier" ::: "memory");
        __builtin_amdgcn_s_setprio(1);
#pragma unroll
        for (int ks = 0; ks < 8; ++ks)
            acc = __builtin_amdgcn_mfma_f32_32x32x16_f16(Ah[ks], b0[ks], acc, 0, 0, 0);
        __builtin_amdgcn_s_setprio(0);
        asm volatile("s_barrier" ::: "memory");

        // ---- phase 2: Bh frag reads + second stage half + cn(u+2) -> 16 MFMA ----
        half8 b1[8];
#pragma unroll
        for (int ks = 0; ks < 8; ++ks)
            b1[ks] = *(const half8*)(bh + ((ks * 2 + lh) * 32 + l31) * 8);
        if (pf) gld16(src + (size_t)(512 + tid) * 8, bufC + (size_t)(512 + tid) * 8);
        float cn2 = pf ? cnorm[c0 + 64] : 0.f;
        asm volatile("s_barrier" ::: "memory");
        __builtin_amdgcn_s_setprio(1);
#pragma unroll
        for (int ks = 0; ks < 8; ++ks) {
            acc = __builtin_amdgcn_mfma_f32_32x32x16_f16(Ah[ks], b1[ks], acc, 0, 0, 0);
            acc = __builtin_amdgcn_mfma_f32_32x32x16_f16(Al[ks], b1[ks], acc, 0, 0, 0);
        }
        __builtin_amdgcn_s_setprio(0);

        // fold dist = cnorm - 2*dot into running argmin
#pragma unroll
        for (int r = 0; r < 16; ++r) {
            float d0 = fmaf(-2.0f, acc[r], cn_cur);
            if (d0 < minv[r]) { minv[r] = d0; mini[r] = c0; }
        }

        // gate: unit u+1's stage (issued at u-1) must be complete before its
        // phase-1 reads. Counted -- exactly unit-u's own 3 issues remain.
        if (u + 2 < NU)      asm volatile("s_waitcnt vmcnt(3)" ::: "memory");
        else if (u + 1 < NU) asm volatile("s_waitcnt vmcnt(0)" ::: "memory"); // tail drain
        asm volatile("s_barrier" ::: "memory");

        cn_cur = cn_nxt; cn_nxt = cn2;
        u16* t = bufA; bufA = bufB; bufB = bufC; bufC = t;   // rotate ring
    }

    // ---- reduce across the 32 l31-lanes sharing each output row ----
#pragma unroll
    for (int r = 0; r < 16; ++r) {
        float v = minv[r];
        int ix = mini[r];
#pragma unroll
        for (int off = 1; off < 32; off <<= 1) {
            float v2 = __shfl_xor(v, off);
            int i2 = __shfl_xor(ix, off);
            if (v2 < v || (v2 == v && i2 < ix)) { v = v2; ix = i2; }
        }
        if (l31 == 0) {
            // C/D row map (m74/m101): row = (reg&3) + 8*(reg>>2) + 4*(lane>>5)
            int row = band * 32 + 4 * lh + (r & 3) + 8 * (r >> 2);
            unsigned int uenc = __float_as_uint(v);
            uenc = (uenc & 0x80000000u) ? ~uenc : (uenc | 0x80000000u);  // monotonic
            u64 pk = ((u64)uenc << 13) | (u64)(unsigned)ix;
            atomicMin(&packed[row], pk);
        }
    }
}

// ---- epilogue: indices, z_q_st, counts, dw ----
__global__ __launch_bounds__(256) void k_epilogue(const float* __restrict__ z_e,
                                                  const float* __restrict__ cb,
                                                  const u64* __restrict__ packed,
                                                  float* __restrict__ out0,
                                                  float* __restrict__ out1,
                                                  float* __restrict__ counts,
                                                  float* __restrict__ dw) {
    __shared__ int idxS[64];
    const int tid = threadIdx.x;
    const int n0 = blockIdx.x * 64;
    const int bb = n0 >> 10, p0 = n0 & 1023;

    if (tid < 64) {
        int ix = (int)(packed[n0 + tid] & 0x1FFFull);
        idxS[tid] = ix;
        out1[n0 + tid] = (float)ix;
        atomicAdd(&counts[ix], 1.0f);
    }
    __syncthreads();

    const float* zb = z_e + (size_t)bb * (D * HW) + p0;
    float* ob = out0 + (size_t)bb * (D * HW) + p0;

    for (int i = tid; i < 64 * D; i += 256) {
        int d = i >> 6, r = i & 63;
        float z = zb[(size_t)d * HW + r];
        float c = cb[(size_t)idxS[r] * D + d];
        ob[(size_t)d * HW + r] = z + (c - z);
    }
    for (int i = tid; i < 64 * D; i += 256) {
        int r = i >> 7, d = i & 127;
        atomicAdd(&dw[(size_t)idxS[r] * D + d], zb[(size_t)d * HW + r]);
    }
}

__global__ __launch_bounds__(256) void k_final(const float* __restrict__ ema_count,
                                               const float* __restrict__ ema_weight,
                                               float* __restrict__ out2,
                                               float* __restrict__ out3,
                                               float* __restrict__ out4) {
    int gid = blockIdx.x * 256 + threadIdx.x;   // over K*D
    int k = gid >> 7, d = gid & 127;
    float cnt_raw = out3[k];
    float dw_raw = out4[gid];
    __syncthreads();
    float nc = 0.99f * ema_count[k] + 0.01f * cnt_raw;
    float nw = 0.99f * ema_weight[gid] + 0.01f * dw_raw;
    out4[gid] = nw;
    out2[gid] = nw / fmaxf(nc, 1.0f);
    if (d == 0) out3[k] = nc;
}

extern "C" void kernel_launch(void* const* d_in, const int* in_sizes, int n_in,
                              void* d_out, int out_size, void* d_ws, size_t ws_size,
                              hipStream_t stream) {
    const float* z_e        = (const float*)d_in[0];
    const float* cb         = (const float*)d_in[1];
    const float* ema_count  = (const float*)d_in[2];
    const float* ema_weight = (const float*)d_in[3];
    float* out = (float*)d_out;

    float* cnorm = (float*)d_ws;                                   // K floats
    u64* packed = (u64*)((char*)d_ws + K * 4);                     // NROWS u64

    // fp16-split scratch lives in out regions rewritten later:
    // out0 (8 MB) hosts Ah|Al, out2 (4 MB) hosts the unit-interleaved B.
    u16* Ahg = (u16*)(out + OUT0);
    u16* Alg = Ahg + (size_t)NROWS * D;
    u16* Bg  = (u16*)(out + OUT2);                                 // 256 units x 16 KiB

    // one-time: allow 48 KiB dynamic LDS for the main kernel (host-side, graph-safe)
    static bool attr_done = false;
    if (!attr_done) {
        hipFuncSetAttribute(reinterpret_cast<const void*>(k_argmin_mfma),
                            hipFuncAttributeMaxDynamicSharedMemorySize, 65536);
        attr_done = true;
    }

    k_prep       <<<1536,          256, 0,     stream>>>(cb, z_e, Bg, cnorm, Ahg, Alg,
                                                         packed, out + OUT3, out + OUT4);
    k_argmin_mfma<<<512,           512, 49152, stream>>>(Ahg, Alg, Bg, cnorm, packed);
    k_epilogue   <<<NROWS / 64,    256, 0,     stream>>>(z_e, cb, packed,
                                                         out + OUT0, out + OUT1,
                                                         out + OUT3, out + OUT4);
    k_final      <<<(K * D) / 256, 256, 0,     stream>>>(ema_count, ema_weight,
                                                         out + OUT2, out + OUT3, out + OUT4);
}

// Round 5
// 208.807 us; speedup vs baseline: 1.0483x; 1.0299x over previous
//
#include <hip/hip_runtime.h>

// Problem constants (B=16, D=128, H=32, W=32, K=8192)
#define D 128
#define HW 1024
#define NROWS 16384
#define K 8192
#define NU 32   // 32-col units per block (1024-col k-split / 32)

// d_out layout (float offsets): z_q_st | indices | new_codebook | new_count | new_weight
#define OUT0 0
#define OUT1 2097152
#define OUT2 2113536
#define OUT3 3162112
#define OUT4 3170304

typedef __attribute__((ext_vector_type(8))) _Float16 half8;
typedef __attribute__((ext_vector_type(16))) float f32x16;
typedef unsigned short u16;
typedef unsigned long long u64;

// ---- async global->LDS, 16B per lane (dst = wave-uniform base + lane*16) ----
__device__ __forceinline__ void gld16(const u16* gsrc, u16* ldst) {
    __builtin_amdgcn_global_load_lds(
        (const __attribute__((address_space(1))) unsigned int*)gsrc,
        (__attribute__((address_space(3))) unsigned int*)ldst,
        16, 0, 0);
}

// ---- fused prep: blocks [0,512) codebook-split + cnorm + dw-zero;
//      blocks [512,1536) z-split + packed-init + counts-zero ----
// B layout: [unit g(256)][ Bh: [kk(16)][col(32)][j(8)] | Bl: same ] (16 KiB/unit)
// A layout: [band(n>>5)][ks(8)][lh(2)][row(32)][j(8)]
__global__ __launch_bounds__(256) void k_prep(const float* __restrict__ cb,
                                              const float* __restrict__ z_e,
                                              u16* __restrict__ Bg,
                                              float* __restrict__ cnorm,
                                              u16* __restrict__ Ah, u16* __restrict__ Al,
                                              u64* __restrict__ packed,
                                              float* __restrict__ counts,
                                              float* __restrict__ dw) {
    const int tid = threadIdx.x;
    if (blockIdx.x < 512) {
        int kk = tid & 15;
        int k = blockIdx.x * 16 + (tid >> 4);
        const float* src = cb + (size_t)k * D + kk * 8;
        half8 h, l;
        float s = 0.f;
#pragma unroll
        for (int j = 0; j < 8; ++j) {
            float v = src[j];
            s += v * v;
            _Float16 hv = (_Float16)v;              // RN f32->f16
            _Float16 lv = (_Float16)(v - (float)hv);
            h[j] = hv;
            l[j] = lv;
        }
        int g = k >> 5, col = k & 31;
        size_t offH = (size_t)g * 8192 + ((size_t)kk * 32 + col) * 8;
        *(half8*)((_Float16*)Bg + offH) = h;
        *(half8*)((_Float16*)Bg + offH + 4096) = l;
#pragma unroll
        for (int off = 8; off > 0; off >>= 1) s += __shfl_down(s, off);
        if (kk == 0) cnorm[k] = s;
        // zero dw: 131072 threads x 8 floats = K*D exactly
        float4 z4 = {0.f, 0.f, 0.f, 0.f};
        size_t zi = ((size_t)blockIdx.x * 256 + tid) * 8;
        *(float4*)(dw + zi) = z4;
        *(float4*)(dw + zi + 4) = z4;
    } else {
        int gid = (blockIdx.x - 512) * 256 + tid;   // NROWS*16 threads
        int n  = gid & (NROWS - 1);                 // lane-contiguous n -> coalesced
        int kk = gid >> 14;                         // 0..15
        int b = n >> 10, hw = n & 1023;
        const float* src = z_e + ((size_t)b * D + kk * 8) * HW + hw;
        half8 h, l;
#pragma unroll
        for (int j = 0; j < 8; ++j) {
            float v = src[(size_t)j * HW];
            _Float16 hv = (_Float16)v;
            _Float16 lv = (_Float16)(v - (float)hv);
            h[j] = hv;
            l[j] = lv;
        }
        int rg = n >> 7, band = (n >> 5) & 3, row = n & 31;
        size_t off = (((((size_t)rg * 4 + band) * 8 + (kk >> 1)) * 2 + (kk & 1)) * 32 + row) * 8;
        *(half8*)(Ah + off) = h;
        *(half8*)(Al + off) = l;
        if (kk == 0) {
            packed[n] = ~0ull;                      // +inf sentinel
            if (n < K) counts[n] = 0.f;
        }
    }
}

// ---- main: 3-pass fp16-split distance GEMM + fused argmin ----
// R5 geometry: the LDS-read pipe was co-equal with MFMA (both ~99K cyc/CU in
// R0/R2/R4 -- schedule changes can't beat max(MFMA,LDS)). Fix the RATIO:
// each wave owns TWO 32-row tiles -> 48 MFMA per 16 ds_read_b128 per unit
// (was 24:16). All four A-frag sets live in VGPRs (128 regs, loop-invariant);
// 256-reg/wave budget via __launch_bounds__(256,2). Blocks: 256 thr (4 waves,
// 64 rows/wave), 2 blocks/CU -> two de-phased barrier groups. Proven R0
// 2-barrier loop; counted vmcnt(5) = this iter's 5 VMEM ops (1 cn + 4 gld16),
// order-robust between the asm fences. Argmin indices packed 2/VGPR.
__global__ __launch_bounds__(256, 2) void k_argmin_mfma(
        const u16* __restrict__ Ahg, const u16* __restrict__ Alg,
        const u16* __restrict__ Bg,
        const float* __restrict__ cnorm, u64* __restrict__ packed) {
    __shared__ u16 lds[2][8192];                // 2 x 16 KiB

    const int tid = threadIdx.x;
    const int ln  = tid & 63;
    const int l31 = ln & 31;
    const int lh  = ln >> 5;                    // k-half select within frag
    const int wy  = tid >> 6;                   // wave 0..3

    // bid -> (rg, ks) swizzle: XCD (bid%8) pins a fixed set of 8 rowgroups,
    // so each rowgroup's A-slab is fetched into one XCD's L2 once (not 8x).
    const int bid = blockIdx.x;                 // 512 = 64 rg x 8 ks
    const int ks_ = (bid >> 3) & 7;
    const int rg  = ((bid & 7) << 3) | (bid >> 6);

    const int k0 = ks_ * 1024;                  // k split
    const int g0 = k0 >> 5;                     // first 32-col B-unit
    const int b0 = rg * 8 + wy * 2;             // wave's two 32-row bands
    const int b1 = b0 + 1;

    // ---- A fragments -> registers (read once from global; 128 VGPRs) ----
    half8 Ah0[8], Al0[8], Ah1[8], Al1[8];
#pragma unroll
    for (int ks = 0; ks < 8; ++ks) {
        size_t o0 = ((((size_t)b0 * 8 + ks) * 2 + lh) * 32 + l31) * 8;
        size_t o1 = ((((size_t)b1 * 8 + ks) * 2 + lh) * 32 + l31) * 8;
        Ah0[ks] = *(const half8*)((const _Float16*)Ahg + o0);
        Al0[ks] = *(const half8*)((const _Float16*)Alg + o0);
        Ah1[ks] = *(const half8*)((const _Float16*)Ahg + o1);
        Al1[ks] = *(const half8*)((const _Float16*)Alg + o1);
    }

    // ---- prologue: stage unit 0 (16 KiB, 4 gld16/thread); full drain ----
    {
        const u16* src = Bg + (size_t)g0 * 8192;
#pragma unroll
        for (int r = 0; r < 4; ++r)
            gld16(src + ((size_t)r * 256 + tid) * 8, lds[0] + (r * 256 + tid) * 8);
    }
    asm volatile("s_waitcnt vmcnt(0)" ::: "memory");
    asm volatile("s_barrier" ::: "memory");

    float    minv0[16], minv1[16];
    unsigned miniP[16];                          // tile0 idx low 16, tile1 high 16
#pragma unroll
    for (int r = 0; r < 16; ++r) { minv0[r] = INFINITY; minv1[r] = INFINITY; miniP[r] = 0; }

#pragma unroll 1
    for (int u = 0; u < NU; ++u) {
        const u16* buf = lds[u & 1];
        const int c0 = k0 + u * 32 + l31;

        // cn use is at the fold (~3000 cyc later); compiler auto-guards the reg dep
        float cn0 = cnorm[c0];

        if (u + 1 < NU) {
            const u16* src = Bg + (size_t)(g0 + u + 1) * 8192;
            u16* dst = lds[(u + 1) & 1];
#pragma unroll
            for (int r = 0; r < 4; ++r)
                gld16(src + ((size_t)r * 256 + tid) * 8, dst + (r * 256 + tid) * 8);
            // exactly this iter's 5 VMEM ops (cn + 4 gld) may stay in flight:
            // everything older (incl. this unit's stage) is retired.
            asm volatile("s_waitcnt vmcnt(5)" ::: "memory");
        } else {
            asm volatile("s_waitcnt vmcnt(0)" ::: "memory");
        }
        asm volatile("s_barrier" ::: "memory");

        f32x16 acc0 = {}, acc1 = {};
        const _Float16* bh = (const _Float16*)buf;
        const _Float16* bl = bh + 4096;

        __builtin_amdgcn_s_setprio(1);
        // pass 1: Ah x Bl (b-frag shared by both row-tiles)
#pragma unroll
        for (int ks = 0; ks < 8; ++ks) {
            const int bo = ((ks * 2 + lh) * 32 + l31) * 8;
            half8 b = *(const half8*)(bl + bo);
            acc0 = __builtin_amdgcn_mfma_f32_32x32x16_f16(Ah0[ks], b, acc0, 0, 0, 0);
            acc1 = __builtin_amdgcn_mfma_f32_32x32x16_f16(Ah1[ks], b, acc1, 0, 0, 0);
        }
        // passes 2+3: Ah x Bh and Al x Bh (b-frag shared 4 ways)
#pragma unroll
        for (int ks = 0; ks < 8; ++ks) {
            const int bo = ((ks * 2 + lh) * 32 + l31) * 8;
            half8 b = *(const half8*)(bh + bo);
            acc0 = __builtin_amdgcn_mfma_f32_32x32x16_f16(Ah0[ks], b, acc0, 0, 0, 0);
            acc1 = __builtin_amdgcn_mfma_f32_32x32x16_f16(Ah1[ks], b, acc1, 0, 0, 0);
            acc0 = __builtin_amdgcn_mfma_f32_32x32x16_f16(Al0[ks], b, acc0, 0, 0, 0);
            acc1 = __builtin_amdgcn_mfma_f32_32x32x16_f16(Al1[ks], b, acc1, 0, 0, 0);
        }
        __builtin_amdgcn_s_setprio(0);

        // fold dist = cnorm - 2*dot into running argmin (both row-tiles)
#pragma unroll
        for (int r = 0; r < 16; ++r) {
            float d0 = fmaf(-2.0f, acc0[r], cn0);
            float d1 = fmaf(-2.0f, acc1[r], cn0);
            bool p0 = d0 < minv0[r];
            bool p1 = d1 < minv1[r];
            minv0[r] = p0 ? d0 : minv0[r];
            minv1[r] = p1 ? d1 : minv1[r];
            miniP[r] = p0 ? ((miniP[r] & 0xFFFF0000u) | (unsigned)c0) : miniP[r];
            miniP[r] = p1 ? ((miniP[r] & 0x0000FFFFu) | ((unsigned)c0 << 16)) : miniP[r];
        }
        // all waves done reading buf before its sibling is overwritten next iter
        asm volatile("s_barrier" ::: "memory");
    }

    // ---- reduce across the 32 l31-lanes sharing each output row ----
#pragma unroll
    for (int t = 0; t < 2; ++t) {
#pragma unroll
        for (int r = 0; r < 16; ++r) {
            float v = (t == 0) ? minv0[r] : minv1[r];
            int ix = (t == 0) ? (int)(miniP[r] & 0xFFFFu) : (int)(miniP[r] >> 16);
#pragma unroll
            for (int off = 1; off < 32; off <<= 1) {
                float v2 = __shfl_xor(v, off);
                int i2 = __shfl_xor(ix, off);
                if (v2 < v || (v2 == v && i2 < ix)) { v = v2; ix = i2; }
            }
            if (l31 == 0) {
                // C/D row map (m74/m101): row = (reg&3) + 8*(reg>>2) + 4*(lane>>5)
                int row = (b0 + t) * 32 + 4 * lh + (r & 3) + 8 * (r >> 2);
                unsigned int uenc = __float_as_uint(v);
                uenc = (uenc & 0x80000000u) ? ~uenc : (uenc | 0x80000000u);  // monotonic
                u64 pk = ((u64)uenc << 13) | (u64)(unsigned)ix;
                atomicMin(&packed[row], pk);
            }
        }
    }
}

// ---- epilogue: indices, z_q_st, counts, dw ----
__global__ __launch_bounds__(256) void k_epilogue(const float* __restrict__ z_e,
                                                  const float* __restrict__ cb,
                                                  const u64* __restrict__ packed,
                                                  float* __restrict__ out0,
                                                  float* __restrict__ out1,
                                                  float* __restrict__ counts,
                                                  float* __restrict__ dw) {
    __shared__ int idxS[64];
    const int tid = threadIdx.x;
    const int n0 = blockIdx.x * 64;
    const int bb = n0 >> 10, p0 = n0 & 1023;

    if (tid < 64) {
        int ix = (int)(packed[n0 + tid] & 0x1FFFull);
        idxS[tid] = ix;
        out1[n0 + tid] = (float)ix;
        atomicAdd(&counts[ix], 1.0f);
    }
    __syncthreads();

    const float* zb = z_e + (size_t)bb * (D * HW) + p0;
    float* ob = out0 + (size_t)bb * (D * HW) + p0;

    for (int i = tid; i < 64 * D; i += 256) {
        int d = i >> 6, r = i & 63;
        float z = zb[(size_t)d * HW + r];
        float c = cb[(size_t)idxS[r] * D + d];
        ob[(size_t)d * HW + r] = z + (c - z);
    }
    for (int i = tid; i < 64 * D; i += 256) {
        int r = i >> 7, d = i & 127;
        atomicAdd(&dw[(size_t)idxS[r] * D + d], zb[(size_t)d * HW + r]);
    }
}

__global__ __launch_bounds__(256) void k_final(const float* __restrict__ ema_count,
                                               const float* __restrict__ ema_weight,
                                               float* __restrict__ out2,
                                               float* __restrict__ out3,
                                               float* __restrict__ out4) {
    int gid = blockIdx.x * 256 + threadIdx.x;   // over K*D
    int k = gid >> 7, d = gid & 127;
    float cnt_raw = out3[k];
    float dw_raw = out4[gid];
    __syncthreads();
    float nc = 0.99f * ema_count[k] + 0.01f * cnt_raw;
    float nw = 0.99f * ema_weight[gid] + 0.01f * dw_raw;
    out4[gid] = nw;
    out2[gid] = nw / fmaxf(nc, 1.0f);
    if (d == 0) out3[k] = nc;
}

extern "C" void kernel_launch(void* const* d_in, const int* in_sizes, int n_in,
                              void* d_out, int out_size, void* d_ws, size_t ws_size,
                              hipStream_t stream) {
    const float* z_e        = (const float*)d_in[0];
    const float* cb         = (const float*)d_in[1];
    const float* ema_count  = (const float*)d_in[2];
    const float* ema_weight = (const float*)d_in[3];
    float* out = (float*)d_out;

    float* cnorm = (float*)d_ws;                                   // K floats
    u64* packed = (u64*)((char*)d_ws + K * 4);                     // NROWS u64

    // fp16-split scratch lives in out regions rewritten later:
    // out0 (8 MB) hosts Ah|Al, out2 (4 MB) hosts the unit-interleaved B.
    u16* Ahg = (u16*)(out + OUT0);
    u16* Alg = Ahg + (size_t)NROWS * D;
    u16* Bg  = (u16*)(out + OUT2);                                 // 256 units x 16 KiB

    k_prep       <<<1536,          256, 0, stream>>>(cb, z_e, Bg, cnorm, Ahg, Alg,
                                                     packed, out + OUT3, out + OUT4);
    k_argmin_mfma<<<512,           256, 0, stream>>>(Ahg, Alg, Bg, cnorm, packed);
    k_epilogue   <<<NROWS / 64,    256, 0, stream>>>(z_e, cb, packed,
                                                     out + OUT0, out + OUT1,
                                                     out + OUT3, out + OUT4);
    k_final      <<<(K * D) / 256, 256, 0, stream>>>(ema_count, ema_weight,
                                                     out + OUT2, out + OUT3, out + OUT4);
}